// Round 6
// baseline (441.853 us; speedup 1.0000x reference)
//
#include <hip/hip_runtime.h>
#include <cstdint>

#define BN 2
#define HN 16
#define NN 2048
#define DD 64
#define KT 64
#define NT (NN / KT)     // 32 tiles
#define LDP 72           // bf16 LDS row stride (Kb/Vt), 144B = 16B-aligned
#define LDB 68           // fp32 LDS row stride (Bb), 272B = 16B-aligned

typedef __attribute__((ext_vector_type(8))) short short8;
typedef __attribute__((ext_vector_type(4))) unsigned short ushort4v;
typedef __attribute__((ext_vector_type(4))) float float4v;

static __device__ __forceinline__ unsigned short f2bf(float f){
    uint32_t u = __builtin_bit_cast(uint32_t, f);
    u += 0x7FFFu + ((u >> 16) & 1u);       // round-to-nearest-even
    return (unsigned short)(u >> 16);
}

static __device__ __forceinline__ float4v mfma_bf16(short8 a, short8 b, float4v c){
    return __builtin_amdgcn_mfma_f32_16x16x32_bf16(a, b, c, 0, 0, 0);
}

// Raw barrier: drain LDS ops only; global loads/stores stay in flight.
static __device__ __forceinline__ void barrier_lds(){
    asm volatile("s_waitcnt lgkmcnt(0)" ::: "memory");
    __builtin_amdgcn_s_barrier();
    asm volatile("" ::: "memory");
}

static __device__ __forceinline__ short8 pack_bf16x8(float4v f0, float4v f1){
    short8 s;
    #pragma unroll
    for(int j = 0; j < 4; ++j){
        s[j]   = (short)f2bf(f0[j]);
        s[4+j] = (short)f2bf(f1[j]);
    }
    return s;
}

__launch_bounds__(256, 4)
__global__ void attn_fused_kernel(const float* __restrict__ Q,
                                  const float* __restrict__ K,
                                  const float* __restrict__ V,
                                  const float* __restrict__ Bias,
                                  float* __restrict__ Out){
    __shared__ unsigned short Kb[KT][LDP];   // K tile [kv_row][d]
    __shared__ unsigned short Vt[DD][LDP];   // V^T tile [d][kv], col XOR-swizzled
    __shared__ float Bb[64][LDB];            // bias / P bounce (block-shared, fp32)

    const int bid = blockIdx.x;
    const int b   = bid & 1;
    const int t2  = bid >> 1;
    const int rt  = t2 & 31;
    const int h   = t2 >> 5;

    const int tid = threadIdx.x;
    const int l   = tid & 63;
    const int w   = tid >> 6;
    const int lg  = l >> 4;           // lane group 0..3
    const int ll  = l & 15;           // lane's q-row within wave tile (swapped layout)

    const int srow = tid >> 4;        // staging row 0..15 (+16*i)
    const int scol = (tid & 15) << 2; // staging col elems 0..60 (16B chunks)
    const int vsw  = (tid & 3) << 3;  // Vt write swizzle = ((d>>2)&3)<<3, d=scol+j
    const int rsw  = ((ll >> 2) & 3) << 3;  // Vt read swizzle for d=16ds+ll

    const int qblk = rt * 64;
    const size_t bh = (size_t)(b * HN + h);
    const float* Qg = Q + (bh * NN + qblk + w * 16) * DD;
    const float* Kg = K + bh * NN * DD;
    const float* Vg = V + bh * NN * DD;
    const float* Bs = Bias + (size_t)h * NN * NN + (size_t)(qblk + srow) * NN + scol;

    // ---- Q fragments (B-frag: lane holds Q[q=ll][k=ks*32+lg*8+e]) ----
    short8 qf[2];
    {
        const float* qrow = Qg + (size_t)ll * DD + lg * 8;
        #pragma unroll
        for(int ks = 0; ks < 2; ++ks)
            qf[ks] = pack_bf16x8(*(const float4v*)(qrow + ks * 32),
                                 *(const float4v*)(qrow + ks * 32 + 4));
    }

    float lsum = 0.f;

    // =============== PASS 1: row sums (swapped QK^T, bias via Bb) ===============
    float4v kreg[4], bv[4];
    #pragma unroll
    for(int i = 0; i < 4; ++i){
        kreg[i] = *(const float4v*)(Kg + (size_t)(srow + 16*i) * DD + scol);
        bv[i]   = *(const float4v*)(Bs + (size_t)(16*i) * NN);
    }

    for(int ct = 0; ct < NT; ++ct){
        barrier_lds();                         // A
        #pragma unroll
        for(int i = 0; i < 4; ++i){            // stage K (b64) + bias (b128), coalesced layout
            ushort4v t;
            #pragma unroll
            for(int j = 0; j < 4; ++j) t[j] = f2bf(kreg[i][j]);
            *(ushort4v*)&Kb[srow + 16*i][scol] = t;
            *(float4v*)&Bb[srow + 16*i][scol]  = bv[i];
        }
        if(ct + 1 < NT){                       // prefetch t+1 (16x256B segments)
            #pragma unroll
            for(int i = 0; i < 4; ++i){
                kreg[i] = *(const float4v*)(Kg + (size_t)((ct+1)*KT + srow + 16*i) * DD + scol);
                bv[i]   = *(const float4v*)(Bs + (size_t)(16*i) * NN + (ct+1)*KT);
            }
        }
        barrier_lds();                         // B

        float4v bb[4];
        #pragma unroll
        for(int sub = 0; sub < 4; ++sub)
            bb[sub] = *(const float4v*)&Bb[w*16 + ll][sub*16 + lg*4];

        float4v acc[4];
        #pragma unroll
        for(int sub = 0; sub < 4; ++sub) acc[sub] = (float4v){0.f,0.f,0.f,0.f};
        __builtin_amdgcn_s_setprio(1);
        #pragma unroll
        for(int sub = 0; sub < 4; ++sub){
            short8 k0 = *(const short8*)&Kb[sub*16 + ll][lg*8];
            short8 k1 = *(const short8*)&Kb[sub*16 + ll][32 + lg*8];
            acc[sub] = mfma_bf16(k0, qf[0], acc[sub]);
            acc[sub] = mfma_bf16(k1, qf[1], acc[sub]);
        }
        __builtin_amdgcn_s_setprio(0);

        #pragma unroll
        for(int sub = 0; sub < 4; ++sub)
            #pragma unroll
            for(int r = 0; r < 4; ++r)
                lsum += __expf(acc[sub][r] * 0.125f + bb[sub][r]);
    }

    // q-row ll partials live at lanes ll, ll+16, ll+32, ll+48
    lsum += __shfl_xor(lsum, 16);
    lsum += __shfl_xor(lsum, 32);
    const float rl = 1.0f / lsum;

    // =============== PASS 2: attn stores + O^T = mfma(V^T, P) ===============
    float4v oacc[4];
    #pragma unroll
    for(int ds = 0; ds < 4; ++ds) oacc[ds] = (float4v){0.f,0.f,0.f,0.f};

    float* attnV = Out + (size_t)BN*HN*NN*DD + (bh * NN + qblk) * (size_t)NN;

    float4v vreg[4];
    #pragma unroll
    for(int i = 0; i < 4; ++i){
        kreg[i] = *(const float4v*)(Kg + (size_t)(srow + 16*i) * DD + scol);
        vreg[i] = *(const float4v*)(Vg + (size_t)(srow + 16*i) * DD + scol);
        bv[i]   = *(const float4v*)(Bs + (size_t)(16*i) * NN);
    }

    for(int ct = 0; ct < NT; ++ct){
        barrier_lds();                         // A
        #pragma unroll
        for(int i = 0; i < 4; ++i){            // stage K + bias + V^T(swizzled)
            ushort4v t;
            #pragma unroll
            for(int j = 0; j < 4; ++j) t[j] = f2bf(kreg[i][j]);
            *(ushort4v*)&Kb[srow + 16*i][scol] = t;
            *(float4v*)&Bb[srow + 16*i][scol]  = bv[i];
            #pragma unroll
            for(int j = 0; j < 4; ++j)
                Vt[scol + j][(srow + 16*i) ^ vsw] = f2bf(vreg[i][j]);
        }
        if(ct + 1 < NT){                       // prefetch t+1
            #pragma unroll
            for(int i = 0; i < 4; ++i){
                kreg[i] = *(const float4v*)(Kg + (size_t)((ct+1)*KT + srow + 16*i) * DD + scol);
                vreg[i] = *(const float4v*)(Vg + (size_t)((ct+1)*KT + srow + 16*i) * DD + scol);
                bv[i]   = *(const float4v*)(Bs + (size_t)(16*i) * NN + (ct+1)*KT);
            }
        }
        barrier_lds();                         // B

        float4v bb[4];
        #pragma unroll
        for(int sub = 0; sub < 4; ++sub)
            bb[sub] = *(const float4v*)&Bb[w*16 + ll][sub*16 + lg*4];

        float4v acc[4];
        #pragma unroll
        for(int sub = 0; sub < 4; ++sub) acc[sub] = (float4v){0.f,0.f,0.f,0.f};
        __builtin_amdgcn_s_setprio(1);
        #pragma unroll
        for(int sub = 0; sub < 4; ++sub){
            short8 k0 = *(const short8*)&Kb[sub*16 + ll][lg*8];
            short8 k1 = *(const short8*)&Kb[sub*16 + ll][32 + lg*8];
            acc[sub] = mfma_bf16(k0, qf[0], acc[sub]);
            acc[sub] = mfma_bf16(k1, qf[1], acc[sub]);
        }
        __builtin_amdgcn_s_setprio(0);

        // p = exp(s)*rl; write in place over consumed bias (same lane, same addr)
        #pragma unroll
        for(int sub = 0; sub < 4; ++sub){
            float4v p4;
            #pragma unroll
            for(int r = 0; r < 4; ++r)
                p4[r] = __expf(acc[sub][r] * 0.125f + bb[sub][r]) * rl;
            *(float4v*)&Bb[w*16 + ll][sub*16 + lg*4] = p4;
        }

        // cross-lane LDS RAW within the wave: drain before re-reads
        asm volatile("s_waitcnt lgkmcnt(0)" ::: "memory");

        // attn store: wave-private vec re-read -> 4 rows x 256B segments
        #pragma unroll
        for(int i = 0; i < 4; ++i){
            float4v pv = *(const float4v*)&Bb[w*16 + lg + 4*i][ll << 2];
            *(float4v*)(attnV + (size_t)(w*16 + lg + 4*i) * NN + ct*KT + (ll << 2)) = pv;
        }

        // P B-frags direct from Bb p-values
        short8 pf[2];
        #pragma unroll
        for(int kb = 0; kb < 2; ++kb){
            float4v f0 = *(const float4v*)&Bb[w*16 + ll][kb*32 + lg*8];
            float4v f1 = *(const float4v*)&Bb[w*16 + ll][kb*32 + lg*8 + 4];
            pf[kb] = pack_bf16x8(f0, f1);
        }

        // PV: O^T[d][q] — A = V^T frag (swizzled Vt), B = P frag
        __builtin_amdgcn_s_setprio(1);
        #pragma unroll
        for(int ds = 0; ds < 4; ++ds){
            short8 v0 = *(const short8*)&Vt[ds*16 + ll][(lg*8) ^ rsw];
            short8 v1 = *(const short8*)&Vt[ds*16 + ll][(32 + lg*8) ^ rsw];
            oacc[ds] = mfma_bf16(v0, pf[0], oacc[ds]);
            oacc[ds] = mfma_bf16(v1, pf[1], oacc[ds]);
        }
        __builtin_amdgcn_s_setprio(0);
    }

    // O store: lane (lg,ll) holds O[q=ll][d=ds*16+lg*4+r] -> float4 stores
    float* outG = Out + (bh * NN + qblk + w*16) * (size_t)DD;
    #pragma unroll
    for(int ds = 0; ds < 4; ++ds)
        *(float4v*)(outG + (size_t)ll * DD + ds*16 + lg*4) = oacc[ds];
}

extern "C" void kernel_launch(void* const* d_in, const int* in_sizes, int n_in,
                              void* d_out, int out_size, void* d_ws, size_t ws_size,
                              hipStream_t stream) {
    const float* q    = (const float*)d_in[0];
    const float* k    = (const float*)d_in[1];
    const float* v    = (const float*)d_in[2];
    const float* bias = (const float*)d_in[3];
    float* out = (float*)d_out;

    dim3 grid(BN * HN * (NN / 64));
    dim3 block(256);
    hipLaunchKernelGGL(attn_fused_kernel, grid, block, 0, stream, q, k, v, bias, out);
}

// Round 7
// 335.133 us; speedup vs baseline: 1.3184x; 1.3184x over previous
//
#include <hip/hip_runtime.h>
#include <cstdint>

#define BN 2
#define HN 16
#define NN 2048
#define DD 64
#define KT 64
#define NT (NN / KT)     // 32 tiles
#define LDP 72           // bf16 LDS row stride (Kb/Vt)
#define LDF 68           // fp32 LDS row stride (Pb)

typedef __attribute__((ext_vector_type(8))) short short8;
typedef __attribute__((ext_vector_type(4))) unsigned short ushort4v;
typedef __attribute__((ext_vector_type(4))) float float4v;

static __device__ __forceinline__ unsigned short f2bf(float f){
    uint32_t u = __builtin_bit_cast(uint32_t, f);
    u += 0x7FFFu + ((u >> 16) & 1u);       // round-to-nearest-even
    return (unsigned short)(u >> 16);
}

static __device__ __forceinline__ float4v mfma_bf16(short8 a, short8 b, float4v c){
    return __builtin_amdgcn_mfma_f32_16x16x32_bf16(a, b, c, 0, 0, 0);
}

// Raw barrier: drain LDS ops only; global loads/stores stay in flight.
static __device__ __forceinline__ void barrier_lds(){
    asm volatile("s_waitcnt lgkmcnt(0)" ::: "memory");
    __builtin_amdgcn_s_barrier();
    asm volatile("" ::: "memory");
}

__launch_bounds__(256, 4)
__global__ void attn_fused_kernel(const float* __restrict__ Q,
                                  const float* __restrict__ K,
                                  const float* __restrict__ V,
                                  const float* __restrict__ Bias,
                                  float* __restrict__ Out){
    __shared__ unsigned short Kb[KT][LDP];   // K tile [kv_row][d]
    __shared__ unsigned short Vt[DD][LDP];   // V^T tile [d][kv], kv XOR-swizzled
    __shared__ float Pb[4][16][LDF];         // per-wave bias/P bounce (fp32)

    const int bid = blockIdx.x;
    const int b   = bid & 1;          // batch innermost: pair shares bias slice via cache
    const int t2  = bid >> 1;
    const int rt  = t2 & 31;
    const int h   = t2 >> 5;

    const int tid = threadIdx.x;
    const int l   = tid & 63;
    const int w   = tid >> 6;
    const int lg  = l >> 4;           // acc-layout row group
    const int ll  = l & 15;           // acc-layout col
    const int vc  = ll * 4;           // vec-layout col

    // coalesced staging coords: wave instr = 4 rows x 256B
    const int srow = tid >> 4;        // 0..15  (+16*i)
    const int scol = (tid & 15) << 2; // element col 0..60
    const int vsw  = ((tid >> 1) & 7) << 3;   // Vt write swizzle, fn of m=(tid&15)

    const int qw = rt * 64 + w * 16;
    const size_t bh = (size_t)(b * HN + h);
    const float* Qg = Q + (bh * NN + qw) * DD;
    const float* Kg = K + bh * NN * DD;
    const float* Vg = V + bh * NN * DD;
    // vec-layout bias base: lane covers rows qw+lg+4*it, cols vc..vc+3
    const float* BgV = Bias + (size_t)h * NN * NN + (size_t)(qw + lg) * NN + vc;

    // ---- Q fragments (A-frag: row=ll, k=ks*32+lg*8+j) ----
    short8 qf[2];
    {
        const float* qrow = Qg + (size_t)ll * DD + lg * 8;
        #pragma unroll
        for(int ks = 0; ks < 2; ++ks){
            float4v f0 = *(const float4v*)(qrow + ks * 32);
            float4v f1 = *(const float4v*)(qrow + ks * 32 + 4);
            short8 s;
            s[0]=(short)f2bf(f0[0]); s[1]=(short)f2bf(f0[1]);
            s[2]=(short)f2bf(f0[2]); s[3]=(short)f2bf(f0[3]);
            s[4]=(short)f2bf(f1[0]); s[5]=(short)f2bf(f1[1]);
            s[6]=(short)f2bf(f1[2]); s[7]=(short)f2bf(f1[3]);
            qf[ks] = s;
        }
    }

    float lsum[4];
    #pragma unroll
    for(int r = 0; r < 4; ++r) lsum[r] = 0.f;

    // =============== PASS 1: per-lane partial row sums (no-max softmax) ===============
    float4v kreg[4], bv[4];
    #pragma unroll
    for(int i = 0; i < 4; ++i)
        kreg[i] = *(const float4v*)(Kg + (size_t)(srow + 16*i) * DD + scol);
    #pragma unroll
    for(int it = 0; it < 4; ++it)
        bv[it] = *(const float4v*)(BgV + (size_t)(it * 4) * NN);

    for(int ct = 0; ct < NT; ++ct){
        barrier_lds();                         // A: waves done reading Kb(t-1)
        #pragma unroll
        for(int i = 0; i < 4; ++i){            // stage K(t): ushort4, coalesced rows
            ushort4v t;
            #pragma unroll
            for(int j = 0; j < 4; ++j) t[j] = f2bf(kreg[i][j]);
            *(ushort4v*)&Kb[srow + 16*i][scol] = t;
        }
        if(ct + 1 < NT){                       // prefetch K(t+1): 4x256B segments/wave
            #pragma unroll
            for(int i = 0; i < 4; ++i)
                kreg[i] = *(const float4v*)(Kg + (size_t)((ct+1)*KT + srow + 16*i) * DD + scol);
        }
        barrier_lds();                         // B: Kb(t) visible

        #pragma unroll
        for(int it = 0; it < 4; ++it)          // stage bias(t) (Pb wave-private)
            *(float4v*)&Pb[w][it*4 + lg][vc] = bv[it];
        if(ct + 1 < NT){
            #pragma unroll
            for(int it = 0; it < 4; ++it)
                bv[it] = *(const float4v*)(BgV + (size_t)(it * 4) * NN + (ct+1)*KT);
        }

        float4v acc[4];
        #pragma unroll
        for(int sub = 0; sub < 4; ++sub) acc[sub] = (float4v){0.f,0.f,0.f,0.f};
        __builtin_amdgcn_s_setprio(1);
        #pragma unroll
        for(int sub = 0; sub < 4; ++sub){
            short8 b0 = *(const short8*)&Kb[sub*16 + ll][lg*8];
            short8 b1 = *(const short8*)&Kb[sub*16 + ll][32 + lg*8];
            acc[sub] = mfma_bf16(qf[0], b0, acc[sub]);
            acc[sub] = mfma_bf16(qf[1], b1, acc[sub]);
        }
        __builtin_amdgcn_s_setprio(0);

        // per-lane partials only; cross-lane reduce deferred to after the loop
        #pragma unroll
        for(int r = 0; r < 4; ++r){
            float e0 = __expf(acc[0][r] * 0.125f + Pb[w][lg*4+r][      ll]);
            float e1 = __expf(acc[1][r] * 0.125f + Pb[w][lg*4+r][16 +  ll]);
            float e2 = __expf(acc[2][r] * 0.125f + Pb[w][lg*4+r][32 +  ll]);
            float e3 = __expf(acc[3][r] * 0.125f + Pb[w][lg*4+r][48 +  ll]);
            lsum[r] += (e0 + e1) + (e2 + e3);
        }
    }

    // one-time reduce across the 16 lanes (ll) of each row group
    float rl[4];
    #pragma unroll
    for(int r = 0; r < 4; ++r){
        #pragma unroll
        for(int d = 1; d < 16; d <<= 1) lsum[r] += __shfl_xor(lsum[r], d);
        rl[r] = 1.0f / lsum[r];
    }

    // =============== PASS 2: write attn (vectorized), O = P*V ===============
    float4v oacc[4];
    #pragma unroll
    for(int ds = 0; ds < 4; ++ds) oacc[ds] = (float4v){0.f,0.f,0.f,0.f};

    float* attnW = Out + (size_t)BN*HN*NN*DD
                 + (bh * NN + qw + lg) * (size_t)NN + vc;

    float4v vreg[4];
    #pragma unroll
    for(int i = 0; i < 4; ++i){
        kreg[i] = *(const float4v*)(Kg + (size_t)(srow + 16*i) * DD + scol);
        vreg[i] = *(const float4v*)(Vg + (size_t)(srow + 16*i) * DD + scol);
    }
    #pragma unroll
    for(int it = 0; it < 4; ++it)
        bv[it] = *(const float4v*)(BgV + (size_t)(it * 4) * NN);

    for(int ct = 0; ct < NT; ++ct){
        barrier_lds();                         // A
        #pragma unroll
        for(int i = 0; i < 4; ++i){            // stage K(t) + V^T(t) swizzled
            ushort4v t;
            #pragma unroll
            for(int j = 0; j < 4; ++j) t[j] = f2bf(kreg[i][j]);
            *(ushort4v*)&Kb[srow + 16*i][scol] = t;
            #pragma unroll
            for(int j = 0; j < 4; ++j)
                Vt[scol + j][(srow + 16*i) ^ vsw] = f2bf(vreg[i][j]);
        }
        if(ct + 1 < NT){                       // prefetch K/V(t+1)
            #pragma unroll
            for(int i = 0; i < 4; ++i){
                kreg[i] = *(const float4v*)(Kg + (size_t)((ct+1)*KT + srow + 16*i) * DD + scol);
                vreg[i] = *(const float4v*)(Vg + (size_t)((ct+1)*KT + srow + 16*i) * DD + scol);
            }
        }
        barrier_lds();                         // B

        #pragma unroll
        for(int it = 0; it < 4; ++it)          // stage bias(t) (wave-private)
            *(float4v*)&Pb[w][it*4 + lg][vc] = bv[it];
        if(ct + 1 < NT){
            #pragma unroll
            for(int it = 0; it < 4; ++it)
                bv[it] = *(const float4v*)(BgV + (size_t)(it * 4) * NN + (ct+1)*KT);
        }

        float4v acc[4];
        #pragma unroll
        for(int sub = 0; sub < 4; ++sub) acc[sub] = (float4v){0.f,0.f,0.f,0.f};
        __builtin_amdgcn_s_setprio(1);
        #pragma unroll
        for(int sub = 0; sub < 4; ++sub){
            short8 b0 = *(const short8*)&Kb[sub*16 + ll][lg*8];
            short8 b1 = *(const short8*)&Kb[sub*16 + ll][32 + lg*8];
            acc[sub] = mfma_bf16(qf[0], b0, acc[sub]);
            acc[sub] = mfma_bf16(qf[1], b1, acc[sub]);
        }
        __builtin_amdgcn_s_setprio(0);

        // p = exp(s)*rl; overwrite bias slot in Pb (same element, same lane)
        #pragma unroll
        for(int sub = 0; sub < 4; ++sub)
            #pragma unroll
            for(int r = 0; r < 4; ++r){
                float sv = acc[sub][r] * 0.125f + Pb[w][lg*4+r][sub*16+ll];
                Pb[w][lg*4+r][sub*16+ll] = __expf(sv) * rl[r];
            }

        // A-fragments for PV from Pb (fp32 -> bf16), cross-lane within wave
        short8 pf0, pf1;
        {
            float4v p0 = *(const float4v*)&Pb[w][ll][lg*8];
            float4v p1 = *(const float4v*)&Pb[w][ll][lg*8 + 4];
            float4v p2 = *(const float4v*)&Pb[w][ll][32 + lg*8];
            float4v p3 = *(const float4v*)&Pb[w][ll][32 + lg*8 + 4];
            #pragma unroll
            for(int j = 0; j < 4; ++j){
                pf0[j]   = (short)f2bf(p0[j]);
                pf0[4+j] = (short)f2bf(p1[j]);
                pf1[j]   = (short)f2bf(p2[j]);
                pf1[4+j] = (short)f2bf(p3[j]);
            }
        }

        // vectorized attn store: 4 x dwordx4/thread, 4x256B segments per wave instr
        #pragma unroll
        for(int it = 0; it < 4; ++it){
            float4v pv = *(const float4v*)&Pb[w][it*4 + lg][vc];
            *(float4v*)(attnW + (size_t)(it*4) * NN + ct*KT) = pv;
        }

        // PV MFMA: B-frags from swizzled Vt (rsw matches write-side vsw)
        __builtin_amdgcn_s_setprio(1);
        #pragma unroll
        for(int ds = 0; ds < 4; ++ds){
            const int rsw = (2*ds + (ll >> 3)) << 3;
            short8 v0 = *(const short8*)&Vt[ds*16 + ll][(lg*8) ^ rsw];
            short8 v1 = *(const short8*)&Vt[ds*16 + ll][(32 + lg*8) ^ rsw];
            oacc[ds] = mfma_bf16(pf0, v0, oacc[ds]);
            oacc[ds] = mfma_bf16(pf1, v1, oacc[ds]);
        }
        __builtin_amdgcn_s_setprio(0);
    }

    // O store
    float* outG = Out + (bh * NN + qw) * (size_t)DD;
    #pragma unroll
    for(int ds = 0; ds < 4; ++ds)
        #pragma unroll
        for(int r = 0; r < 4; ++r)
            outG[(size_t)(lg*4 + r) * DD + ds*16 + ll] = oacc[ds][r];
}

extern "C" void kernel_launch(void* const* d_in, const int* in_sizes, int n_in,
                              void* d_out, int out_size, void* d_ws, size_t ws_size,
                              hipStream_t stream) {
    const float* q    = (const float*)d_in[0];
    const float* k    = (const float*)d_in[1];
    const float* v    = (const float*)d_in[2];
    const float* bias = (const float*)d_in[3];
    float* out = (float*)d_out;

    dim3 grid(BN * HN * (NN / 64));
    dim3 block(256);
    hipLaunchKernelGGL(attn_fused_kernel, grid, block, 0, stream, q, k, v, bias, out);
}

// Round 8
// 324.317 us; speedup vs baseline: 1.3624x; 1.0333x over previous
//
#include <hip/hip_runtime.h>
#include <cstdint>

#define BN 2
#define HN 16
#define NN 2048
#define DD 64
#define KT 64
#define NT (NN / KT)     // 32 tiles
#define LDP 72           // bf16 LDS row stride (Kb/Vt)
#define LDF 68           // fp32 LDS row stride (Pb)

typedef __attribute__((ext_vector_type(8))) short short8;
typedef __attribute__((ext_vector_type(2))) uint32_t uint2v;
typedef __attribute__((ext_vector_type(4))) uint32_t uint4v;
typedef __attribute__((ext_vector_type(4))) float float4v;

// Hardware packed convert: dst.lo = bf16(a), dst.hi = bf16(b). RTNE, same as
// the previous manual round-to-nearest-even bit-twiddle -> identical numerics,
// ~1/8 the VALU instructions.
static __device__ __forceinline__ uint32_t cvt_pk_bf16(float a, float b){
    uint32_t r;
    asm("v_cvt_pk_bf16_f32 %0, %1, %2" : "=v"(r) : "v"(a), "v"(b));
    return r;
}
static __device__ __forceinline__ unsigned short f2bf1(float a){
    return (unsigned short)(cvt_pk_bf16(a, a) & 0xffffu);
}

static __device__ __forceinline__ float4v mfma_bf16(short8 a, short8 b, float4v c){
    return __builtin_amdgcn_mfma_f32_16x16x32_bf16(a, b, c, 0, 0, 0);
}

// Raw barrier: drain LDS ops only; global loads/stores stay in flight.
static __device__ __forceinline__ void barrier_lds(){
    asm volatile("s_waitcnt lgkmcnt(0)" ::: "memory");
    __builtin_amdgcn_s_barrier();
    asm volatile("" ::: "memory");
}

__launch_bounds__(256, 4)
__global__ void attn_fused_kernel(const float* __restrict__ Q,
                                  const float* __restrict__ K,
                                  const float* __restrict__ V,
                                  const float* __restrict__ Bias,
                                  float* __restrict__ Out){
    __shared__ unsigned short Kb[KT][LDP];   // K tile [kv_row][d]
    __shared__ unsigned short Vt[DD][LDP];   // V^T tile [d][kv], kv XOR-swizzled
    __shared__ float Pb[4][16][LDF];         // per-wave bias/P bounce (fp32)

    // XCD-aware decode: dispatch round-robins bid%8 across XCDs. Give each
    // XCD slot 2 whole heads (bias slice + K/V become L2-resident) and keep
    // the b=0/b=1 bias-sharing pair on the same XCD (idx&1).
    const int raw  = blockIdx.x;
    const int slot = raw & 7;
    const int idx  = raw >> 3;
    const int b    = idx & 1;
    const int ghr  = slot * 64 + (idx >> 1);   // 0..511 = (h,rt)
    const int h    = ghr >> 5;
    const int rt   = ghr & 31;

    const int tid = threadIdx.x;
    const int l   = tid & 63;
    const int w   = tid >> 6;
    const int lg  = l >> 4;           // acc-layout row group
    const int ll  = l & 15;           // acc-layout col
    const int vc  = ll * 4;           // vec-layout col

    // coalesced staging coords: wave instr = 4 rows x 256B
    const int srow = tid >> 4;        // 0..15  (+16*i)
    const int scol = (tid & 15) << 2; // element col 0..60
    const int vsw  = ((tid >> 1) & 7) << 3;   // Vt write swizzle

    const int qw = rt * 64 + w * 16;
    const size_t bh = (size_t)(b * HN + h);
    const float* Qg = Q + (bh * NN + qw) * DD;
    const float* Kg = K + bh * NN * DD;
    const float* Vg = V + bh * NN * DD;
    const float* BgV = Bias + (size_t)h * NN * NN + (size_t)(qw + lg) * NN + vc;

    // ---- Q fragments (A-frag: row=ll, k=ks*32+lg*8+j) ----
    short8 qf[2];
    {
        const float* qrow = Qg + (size_t)ll * DD + lg * 8;
        #pragma unroll
        for(int ks = 0; ks < 2; ++ks){
            float4v f0 = *(const float4v*)(qrow + ks * 32);
            float4v f1 = *(const float4v*)(qrow + ks * 32 + 4);
            uint4v u;
            u[0] = cvt_pk_bf16(f0[0], f0[1]);
            u[1] = cvt_pk_bf16(f0[2], f0[3]);
            u[2] = cvt_pk_bf16(f1[0], f1[1]);
            u[3] = cvt_pk_bf16(f1[2], f1[3]);
            qf[ks] = __builtin_bit_cast(short8, u);
        }
    }

    float lsum[4];
    #pragma unroll
    for(int r = 0; r < 4; ++r) lsum[r] = 0.f;

    // =============== PASS 1: per-lane partial row sums (no-max softmax) ===============
    float4v kreg[4], bv[4];
    #pragma unroll
    for(int i = 0; i < 4; ++i)
        kreg[i] = *(const float4v*)(Kg + (size_t)(srow + 16*i) * DD + scol);
    #pragma unroll
    for(int it = 0; it < 4; ++it)
        bv[it] = *(const float4v*)(BgV + (size_t)(it * 4) * NN);

    for(int ct = 0; ct < NT; ++ct){
        barrier_lds();                         // A: waves done reading Kb(t-1)
        #pragma unroll
        for(int i = 0; i < 4; ++i){            // stage K(t): 2 cvt_pk + b64 write
            uint2v t = { cvt_pk_bf16(kreg[i][0], kreg[i][1]),
                         cvt_pk_bf16(kreg[i][2], kreg[i][3]) };
            *(uint2v*)&Kb[srow + 16*i][scol] = t;
        }
        if(ct + 1 < NT){                       // prefetch K(t+1)
            #pragma unroll
            for(int i = 0; i < 4; ++i)
                kreg[i] = *(const float4v*)(Kg + (size_t)((ct+1)*KT + srow + 16*i) * DD + scol);
        }
        barrier_lds();                         // B: Kb(t) visible

        #pragma unroll
        for(int it = 0; it < 4; ++it)          // stage bias(t) (Pb wave-private)
            *(float4v*)&Pb[w][it*4 + lg][vc] = bv[it];
        if(ct + 1 < NT){
            #pragma unroll
            for(int it = 0; it < 4; ++it)
                bv[it] = *(const float4v*)(BgV + (size_t)(it * 4) * NN + (ct+1)*KT);
        }

        float4v acc[4];
        #pragma unroll
        for(int sub = 0; sub < 4; ++sub) acc[sub] = (float4v){0.f,0.f,0.f,0.f};
        __builtin_amdgcn_s_setprio(1);
        #pragma unroll
        for(int sub = 0; sub < 4; ++sub){
            short8 b0 = *(const short8*)&Kb[sub*16 + ll][lg*8];
            short8 b1 = *(const short8*)&Kb[sub*16 + ll][32 + lg*8];
            acc[sub] = mfma_bf16(qf[0], b0, acc[sub]);
            acc[sub] = mfma_bf16(qf[1], b1, acc[sub]);
        }
        __builtin_amdgcn_s_setprio(0);

        #pragma unroll
        for(int r = 0; r < 4; ++r){
            float e0 = __expf(acc[0][r] * 0.125f + Pb[w][lg*4+r][      ll]);
            float e1 = __expf(acc[1][r] * 0.125f + Pb[w][lg*4+r][16 +  ll]);
            float e2 = __expf(acc[2][r] * 0.125f + Pb[w][lg*4+r][32 +  ll]);
            float e3 = __expf(acc[3][r] * 0.125f + Pb[w][lg*4+r][48 +  ll]);
            lsum[r] += (e0 + e1) + (e2 + e3);
        }
    }

    float rl[4];
    #pragma unroll
    for(int r = 0; r < 4; ++r){
        #pragma unroll
        for(int d = 1; d < 16; d <<= 1) lsum[r] += __shfl_xor(lsum[r], d);
        rl[r] = 1.0f / lsum[r];
    }

    // =============== PASS 2: write attn (vectorized), O = P*V ===============
    float4v oacc[4];
    #pragma unroll
    for(int ds = 0; ds < 4; ++ds) oacc[ds] = (float4v){0.f,0.f,0.f,0.f};

    float* attnW = Out + (size_t)BN*HN*NN*DD
                 + (bh * NN + qw + lg) * (size_t)NN + vc;

    float4v vreg[4];
    #pragma unroll
    for(int i = 0; i < 4; ++i){
        kreg[i] = *(const float4v*)(Kg + (size_t)(srow + 16*i) * DD + scol);
        vreg[i] = *(const float4v*)(Vg + (size_t)(srow + 16*i) * DD + scol);
    }
    #pragma unroll
    for(int it = 0; it < 4; ++it)
        bv[it] = *(const float4v*)(BgV + (size_t)(it * 4) * NN);

    for(int ct = 0; ct < NT; ++ct){
        barrier_lds();                         // A
        #pragma unroll
        for(int i = 0; i < 4; ++i){            // stage K(t) + V^T(t) swizzled
            uint2v t = { cvt_pk_bf16(kreg[i][0], kreg[i][1]),
                         cvt_pk_bf16(kreg[i][2], kreg[i][3]) };
            *(uint2v*)&Kb[srow + 16*i][scol] = t;
            #pragma unroll
            for(int j = 0; j < 4; ++j)
                Vt[scol + j][(srow + 16*i) ^ vsw] = f2bf1(vreg[i][j]);
        }
        if(ct + 1 < NT){                       // prefetch K/V(t+1)
            #pragma unroll
            for(int i = 0; i < 4; ++i){
                kreg[i] = *(const float4v*)(Kg + (size_t)((ct+1)*KT + srow + 16*i) * DD + scol);
                vreg[i] = *(const float4v*)(Vg + (size_t)((ct+1)*KT + srow + 16*i) * DD + scol);
            }
        }
        barrier_lds();                         // B

        #pragma unroll
        for(int it = 0; it < 4; ++it)          // stage bias(t) (wave-private)
            *(float4v*)&Pb[w][it*4 + lg][vc] = bv[it];
        if(ct + 1 < NT){
            #pragma unroll
            for(int it = 0; it < 4; ++it)
                bv[it] = *(const float4v*)(BgV + (size_t)(it * 4) * NN + (ct+1)*KT);
        }

        float4v acc[4];
        #pragma unroll
        for(int sub = 0; sub < 4; ++sub) acc[sub] = (float4v){0.f,0.f,0.f,0.f};
        __builtin_amdgcn_s_setprio(1);
        #pragma unroll
        for(int sub = 0; sub < 4; ++sub){
            short8 b0 = *(const short8*)&Kb[sub*16 + ll][lg*8];
            short8 b1 = *(const short8*)&Kb[sub*16 + ll][32 + lg*8];
            acc[sub] = mfma_bf16(qf[0], b0, acc[sub]);
            acc[sub] = mfma_bf16(qf[1], b1, acc[sub]);
        }
        __builtin_amdgcn_s_setprio(0);

        // p = exp(s)*rl; overwrite bias slot in Pb (same element, same lane)
        #pragma unroll
        for(int sub = 0; sub < 4; ++sub)
            #pragma unroll
            for(int r = 0; r < 4; ++r){
                float sv = acc[sub][r] * 0.125f + Pb[w][lg*4+r][sub*16+ll];
                Pb[w][lg*4+r][sub*16+ll] = __expf(sv) * rl[r];
            }

        // A-fragments for PV from Pb (fp32 -> bf16 via cvt_pk)
        short8 pf0, pf1;
        {
            float4v p0 = *(const float4v*)&Pb[w][ll][lg*8];
            float4v p1 = *(const float4v*)&Pb[w][ll][lg*8 + 4];
            float4v p2 = *(const float4v*)&Pb[w][ll][32 + lg*8];
            float4v p3 = *(const float4v*)&Pb[w][ll][32 + lg*8 + 4];
            uint4v u0, u1;
            u0[0] = cvt_pk_bf16(p0[0], p0[1]);
            u0[1] = cvt_pk_bf16(p0[2], p0[3]);
            u0[2] = cvt_pk_bf16(p1[0], p1[1]);
            u0[3] = cvt_pk_bf16(p1[2], p1[3]);
            u1[0] = cvt_pk_bf16(p2[0], p2[1]);
            u1[1] = cvt_pk_bf16(p2[2], p2[3]);
            u1[2] = cvt_pk_bf16(p3[0], p3[1]);
            u1[3] = cvt_pk_bf16(p3[2], p3[3]);
            pf0 = __builtin_bit_cast(short8, u0);
            pf1 = __builtin_bit_cast(short8, u1);
        }

        // vectorized attn store: 4 x dwordx4/thread
        #pragma unroll
        for(int it = 0; it < 4; ++it){
            float4v pv = *(const float4v*)&Pb[w][it*4 + lg][vc];
            *(float4v*)(attnW + (size_t)(it*4) * NN + ct*KT) = pv;
        }

        // PV MFMA: B-frags from swizzled Vt
        __builtin_amdgcn_s_setprio(1);
        #pragma unroll
        for(int ds = 0; ds < 4; ++ds){
            const int rsw = (2*ds + (ll >> 3)) << 3;
            short8 v0 = *(const short8*)&Vt[ds*16 + ll][(lg*8) ^ rsw];
            short8 v1 = *(const short8*)&Vt[ds*16 + ll][(32 + lg*8) ^ rsw];
            oacc[ds] = mfma_bf16(pf0, v0, oacc[ds]);
            oacc[ds] = mfma_bf16(pf1, v1, oacc[ds]);
        }
        __builtin_amdgcn_s_setprio(0);
    }

    // O store
    float* outG = Out + (bh * NN + qw) * (size_t)DD;
    #pragma unroll
    for(int ds = 0; ds < 4; ++ds)
        #pragma unroll
        for(int r = 0; r < 4; ++r)
            outG[(size_t)(lg*4 + r) * DD + ds*16 + ll] = oacc[ds][r];
}

extern "C" void kernel_launch(void* const* d_in, const int* in_sizes, int n_in,
                              void* d_out, int out_size, void* d_ws, size_t ws_size,
                              hipStream_t stream) {
    const float* q    = (const float*)d_in[0];
    const float* k    = (const float*)d_in[1];
    const float* v    = (const float*)d_in[2];
    const float* bias = (const float*)d_in[3];
    float* out = (float*)d_out;

    dim3 grid(BN * HN * (NN / 64));
    dim3 block(256);
    hipLaunchKernelGGL(attn_fused_kernel, grid, block, 0, stream, q, k, v, bias, out);
}